// Round 1
// baseline (918.133 us; speedup 1.0000x reference)
//
#include <hip/hip_runtime.h>
#include <hip/hip_bf16.h>
#include <stdint.h>

typedef unsigned short u16;
// Guide §3: HIP vector type for bf16 16x16x32 fragments (4 VGPRs)
typedef __attribute__((ext_vector_type(8))) short bf16x8;
typedef __attribute__((ext_vector_type(4))) float f32x4;

__device__ __forceinline__ u16 f2bf(float f) {
    union { float f; uint32_t u; } c; c.f = f;
    uint32_t u = c.u;
    uint32_t r = (u + 0x7FFFu + ((u >> 16) & 1u)) >> 16;  // RNE
    return (u16)r;
}

__device__ __forceinline__ void gload_lds16(const void* g, void* l) {
    __builtin_amdgcn_global_load_lds(
        (const __attribute__((address_space(1))) void*)g,
        (__attribute__((address_space(3))) void*)l, 16, 0, 0);
}

// ---------------- f32 -> bf16 convert, float4/ushort4 vectorized ----------------
__global__ __launch_bounds__(256) void cvt_f32_bf16(const float4* __restrict__ in,
                                                    ushort4* __restrict__ out, int n4) {
    int i = blockIdx.x * blockDim.x + threadIdx.x;
    int stride = gridDim.x * blockDim.x;
    for (; i < n4; i += stride) {
        float4 v = in[i];
        ushort4 o;
        o.x = f2bf(v.x); o.y = f2bf(v.y); o.z = f2bf(v.z); o.w = f2bf(v.w);
        out[i] = o;
    }
}

// ---------------- T[i][r] = S[r] * Vh[r][i], bf16 out (64x64 LDS tile) ----------------
__global__ __launch_bounds__(256) void svh_transpose(const float* __restrict__ Vh,
                                                     const float* __restrict__ S,
                                                     u16* __restrict__ T, int R, int Din) {
    __shared__ u16 tile[64][66];  // +2 pad: write stride 132B -> conflict-free
    int nbi = Din >> 6;
    int i0 = (blockIdx.x % nbi) << 6;
    int r0 = (blockIdx.x / nbi) << 6;
    int tx = threadIdx.x & 63, ty = threadIdx.x >> 6;
    for (int rr = ty; rr < 64; rr += 4) {
        float s = S[r0 + rr];
        float v = Vh[(size_t)(r0 + rr) * Din + i0 + tx] * s;
        tile[tx][rr] = f2bf(v);  // store transposed
    }
    __syncthreads();
    int cg = threadIdx.x & 15, ri = threadIdx.x >> 4;
#pragma unroll
    for (int j = 0; j < 4; ++j) {
        int ii = (j << 4) + ri;
        ushort4 o;
        o.x = tile[ii][cg * 4 + 0]; o.y = tile[ii][cg * 4 + 1];
        o.z = tile[ii][cg * 4 + 2]; o.w = tile[ii][cg * 4 + 3];
        *(ushort4*)&T[(size_t)(i0 + ii) * R + r0 + cg * 4] = o;
    }
}

// ---------------- NT GEMM: C[M][N] = A[M][K] * B[N][K]^T, bf16 in, f32 or bf16 out ----
// m97 structure: 128x128 tile, BK=32, 4 waves (2x2), 4x4 16x16x32 fragments per wave,
// global_load_lds width-16 staging, single LDS buffer, 2 barriers per K-step.
template <int OUT_F32>
__global__ __launch_bounds__(256) void gemm_nt(const u16* __restrict__ A,
                                               const u16* __restrict__ B,
                                               void* __restrict__ Cv,
                                               int M, int N, int K) {
    __shared__ u16 As[128 * 32];
    __shared__ u16 Bs[128 * 32];
    const int tid  = threadIdx.x;
    const int lane = tid & 63;
    const int wave = tid >> 6;
    const int wr = wave >> 1, wc = wave & 1;   // 2x2 wave grid, each wave 64x64
    const int fr = lane & 15, fq = lane >> 4;  // fragment row/col, k-quad

    // XCD-aware swizzle (grids are multiples of 8)
    const int nbx = N >> 7;
    const int bid = (int)blockIdx.x;
    const int cpx = (int)gridDim.x >> 3;
    const int swz = (bid & 7) * cpx + (bid >> 3);
    const int brow = (swz / nbx) << 7;
    const int bcol = (swz % nbx) << 7;

    f32x4 acc[4][4] = {};

    const int r0 = tid >> 2;        // staging row 0..63
    const int ko = (tid & 3) << 3;  // staging k-offset in elems (0,8,16,24)

    for (int kt = 0; kt < K; kt += 32) {
        // stage 16KB: A[128][32] + B[128][32]; LDS dest = wave-uniform base + lane*16B
        gload_lds16(&A[(size_t)(brow + r0) * K + kt + ko],      &As[tid * 8]);
        gload_lds16(&A[(size_t)(brow + 64 + r0) * K + kt + ko], &As[2048 + tid * 8]);
        gload_lds16(&B[(size_t)(bcol + r0) * K + kt + ko],      &Bs[tid * 8]);
        gload_lds16(&B[(size_t)(bcol + 64 + r0) * K + kt + ko], &Bs[2048 + tid * 8]);
        __syncthreads();  // compiler drains vmcnt before s_barrier

        bf16x8 af[4], bf[4];
#pragma unroll
        for (int m = 0; m < 4; ++m)
            af[m] = *(const bf16x8*)&As[((wr * 64 + m * 16 + fr) << 5) + (fq << 3)];
#pragma unroll
        for (int n = 0; n < 4; ++n)
            bf[n] = *(const bf16x8*)&Bs[((wc * 64 + n * 16 + fr) << 5) + (fq << 3)];
#pragma unroll
        for (int m = 0; m < 4; ++m)
#pragma unroll
            for (int n = 0; n < 4; ++n)
                acc[m][n] = __builtin_amdgcn_mfma_f32_16x16x32_bf16(af[m], bf[n], acc[m][n], 0, 0, 0);
        __syncthreads();
    }

    // C/D layout (m89-verified): col = lane&15, row = (lane>>4)*4 + j
    if (OUT_F32) {
        float* C = (float*)Cv;
#pragma unroll
        for (int m = 0; m < 4; ++m)
#pragma unroll
            for (int n = 0; n < 4; ++n)
#pragma unroll
                for (int j = 0; j < 4; ++j) {
                    int r = brow + wr * 64 + m * 16 + fq * 4 + j;
                    int c = bcol + wc * 64 + n * 16 + fr;
                    C[(size_t)r * N + c] = acc[m][n][j];
                }
    } else {
        u16* C = (u16*)Cv;
#pragma unroll
        for (int m = 0; m < 4; ++m)
#pragma unroll
            for (int n = 0; n < 4; ++n)
#pragma unroll
                for (int j = 0; j < 4; ++j) {
                    int r = brow + wr * 64 + m * 16 + fq * 4 + j;
                    int c = bcol + wc * 64 + n * 16 + fr;
                    C[(size_t)r * N + c] = f2bf(acc[m][n][j]);
                }
    }
}

extern "C" void kernel_launch(void* const* d_in, const int* in_sizes, int n_in,
                              void* d_out, int out_size, void* d_ws, size_t ws_size,
                              hipStream_t stream) {
    const float* x  = (const float*)d_in[0];   // [4,2048,4096]
    const float* U  = (const float*)d_in[1];   // [4096,4096]
    const float* S  = (const float*)d_in[2];   // [4096]
    const float* Vh = (const float*)d_in[3];   // [4096,4096]
    float* out = (float*)d_out;                // [4,2048,4096] f32

    const int DIN = 4096, DOUT = 4096, R = 4096;
    const int Mx = 4 * 2048;  // 8192 rows of x

    // d_ws scratch: Xb (64MB) + Wb (32MB) = 96MB
    u16* Xb = (u16*)d_ws;
    u16* Wb = (u16*)((char*)d_ws + (size_t)Mx * DIN * 2);
    // d_out doubles as scratch for operands dead before GEMM2 writes out:
    u16* Ub   = (u16*)d_out;                                  // 32MB
    u16* SVhT = (u16*)((char*)d_out + (size_t)DOUT * R * 2);  // 32MB

    cvt_f32_bf16<<<2048, 256, 0, stream>>>((const float4*)x, (ushort4*)Xb, Mx * DIN / 4);
    cvt_f32_bf16<<<1024, 256, 0, stream>>>((const float4*)U, (ushort4*)Ub, DOUT * R / 4);
    svh_transpose<<<(R / 64) * (DIN / 64), 256, 0, stream>>>(Vh, S, SVhT, R, DIN);
    // GEMM1: Wb[o][i] = sum_r Ub[o][r] * SVhT[i][r]   (bf16 out)
    gemm_nt<0><<<(DOUT / 128) * (DIN / 128), 256, 0, stream>>>(Ub, SVhT, (void*)Wb, DOUT, DIN, R);
    // GEMM2: out[m][o] = sum_d Xb[m][d] * Wb[o][d]    (f32 out)
    gemm_nt<1><<<(Mx / 128) * (DOUT / 128), 256, 0, stream>>>(Xb, Wb, (void*)out, Mx, DOUT, DIN);
}

// Round 2
// 675.806 us; speedup vs baseline: 1.3586x; 1.3586x over previous
//
#include <hip/hip_runtime.h>
#include <hip/hip_bf16.h>
#include <stdint.h>

typedef unsigned short u16;
typedef __attribute__((ext_vector_type(8))) short bf16x8;
typedef __attribute__((ext_vector_type(4))) float f32x4;

__device__ __forceinline__ u16 f2bf(float f) {
    union { float f; uint32_t u; } c; c.f = f;
    uint32_t u = c.u;
    return (u16)((u + 0x7FFFu + ((u >> 16) & 1u)) >> 16);  // RNE
}

__device__ __forceinline__ void gload_lds16(const void* g, void* l) {
    __builtin_amdgcn_global_load_lds(
        (const __attribute__((address_space(1))) void*)g,
        (__attribute__((address_space(3))) void*)l, 16, 0, 0);
}

// raw barrier, compile-time fenced both sides (rule #18 / m152)
#define SBAR() do { __builtin_amdgcn_sched_barrier(0); __builtin_amdgcn_s_barrier(); \
                    __builtin_amdgcn_sched_barrier(0); } while (0)

// ---------------- f32 -> bf16 convert ----------------
__global__ __launch_bounds__(256) void cvt_f32_bf16(const float4* __restrict__ in,
                                                    ushort4* __restrict__ out, int n4) {
    int i = blockIdx.x * blockDim.x + threadIdx.x;
    int stride = gridDim.x * blockDim.x;
    for (; i < n4; i += stride) {
        float4 v = in[i];
        ushort4 o;
        o.x = f2bf(v.x); o.y = f2bf(v.y); o.z = f2bf(v.z); o.w = f2bf(v.w);
        out[i] = o;
    }
}

// ---------------- T[i][r] = S[r] * Vh[r][i], bf16 out ----------------
__global__ __launch_bounds__(256) void svh_transpose(const float* __restrict__ Vh,
                                                     const float* __restrict__ S,
                                                     u16* __restrict__ T, int R, int Din) {
    __shared__ u16 tile[64][66];
    int nbi = Din >> 6;
    int i0 = (blockIdx.x % nbi) << 6;
    int r0 = (blockIdx.x / nbi) << 6;
    int tx = threadIdx.x & 63, ty = threadIdx.x >> 6;
    for (int rr = ty; rr < 64; rr += 4) {
        float s = S[r0 + rr];
        float v = Vh[(size_t)(r0 + rr) * Din + i0 + tx] * s;
        tile[tx][rr] = f2bf(v);
    }
    __syncthreads();
    int cg = threadIdx.x & 15, ri = threadIdx.x >> 4;
#pragma unroll
    for (int j = 0; j < 4; ++j) {
        int ii = (j << 4) + ri;
        ushort4 o;
        o.x = tile[ii][cg * 4 + 0]; o.y = tile[ii][cg * 4 + 1];
        o.z = tile[ii][cg * 4 + 2]; o.w = tile[ii][cg * 4 + 3];
        *(ushort4*)&T[(size_t)(i0 + ii) * R + r0 + cg * 4] = o;
    }
}

// ---------------- Deep-pipelined NT GEMM: C[M][N] = A[M][K] * B[N][K]^T ----------------
// 256x256 tile, BK=32, 8 waves (2Mx4N), per-wave 128x64 out, acc[8][4].
// LDS 128KB: 4-deep ring of {A:256x32, B:256x32} bf16 units (16KB each).
// Stage 3 K-tiles ahead via global_load_lds w16; counted vmcnt(8) once per tile (T3+T4).
// k-slot XOR swizzle s' = fq ^ ((r>>1)&3): inverse-permuted global source on the write
// side (linear gload_lds dest), swizzled ds_read addr on the read side (T2, rule #21).
template <int OUT_F32>
__global__ __launch_bounds__(512, 2) void gemm_nt_pipe(const u16* __restrict__ A,
                                                       const u16* __restrict__ B,
                                                       void* __restrict__ Cv,
                                                       int M, int N, int K) {
    __shared__ u16 lds[65536];  // 128 KiB: A units [0,32768), B units [32768,65536)
    const int tid  = (int)threadIdx.x;
    const int lane = tid & 63;
    const int wave = tid >> 6;
    const int wr = wave >> 2;     // 0..1  (M wave group)
    const int wc = wave & 3;      // 0..3  (N wave group)
    const int fr = lane & 15;
    const int fq = lane >> 4;
    const int sp = fq ^ ((fr >> 1) & 3);  // swizzled k-slot for ds_read

    // XCD-aware swizzle (grid % 8 == 0)
    const int nbx = N >> 8;
    const int bid = (int)blockIdx.x;
    const int cpx = (int)gridDim.x >> 3;
    const int swz = (bid & 7) * cpx + (bid >> 3);
    const int brow = (swz / nbx) << 8;
    const int bcol = (swz % nbx) << 8;

    // staging decode: chunk c = (issue*8 + wave)*64 + lane; r = c>>2, s = (c&3)^((r>>1)&3)
    const int c0 = wave * 64 + lane;
    const int c1 = c0 + 512;
    const int r0 = c0 >> 2, s0 = (c0 & 3) ^ ((r0 >> 1) & 3);
    const int r1 = c1 >> 2, s1 = (c1 & 3) ^ ((r1 >> 1) & 3);
    const u16* gA0 = A + (size_t)(brow + r0) * K + s0 * 8;
    const u16* gA1 = A + (size_t)(brow + r1) * K + s1 * 8;
    const u16* gB0 = B + (size_t)(bcol + r0) * K + s0 * 8;
    const u16* gB1 = B + (size_t)(bcol + r1) * K + s1 * 8;

    // per-lane ds_read bases (elem units); fragment row stride = 512 elems (16 rows * 32)
    const int aoff = wr * 4096 + fr * 32 + sp * 8;
    const int boff = 32768 + wc * 2048 + fr * 32 + sp * 8;

    f32x4 acc[8][4] = {};

#define STAGE_A(bufi, kt) do { gload_lds16(gA0 + (kt), &lds[(bufi) * 8192 + c0 * 8]); \
                               gload_lds16(gA1 + (kt), &lds[(bufi) * 8192 + c1 * 8]); } while (0)
#define STAGE_B(bufi, kt) do { gload_lds16(gB0 + (kt), &lds[32768 + (bufi) * 8192 + c0 * 8]); \
                               gload_lds16(gB1 + (kt), &lds[32768 + (bufi) * 8192 + c1 * 8]); } while (0)

    // prologue: stage tiles 0,1,2 (12 loads/thread); wait tile 0 (leave 8 in flight)
    STAGE_A(0, 0);  STAGE_B(0, 0);
    STAGE_A(1, 32); STAGE_B(1, 32);
    STAGE_A(2, 64); STAGE_B(2, 64);
    asm volatile("s_waitcnt vmcnt(8)" ::: "memory");
    SBAR();

    const int NT = K >> 5;
#pragma unroll 1
    for (int t = 0; t < NT; ++t) {
        const int buf = t & 3;
        const u16* la = &lds[buf * 8192 + aoff];
        const u16* lb = &lds[buf * 8192 + boff];
        bf16x8 af[8], bf[4];

        // ---- phase 1: read A frags + B n0-1, stage next A unit, MFMA quadrant ----
#pragma unroll
        for (int i = 0; i < 8; ++i) af[i] = *(const bf16x8*)(la + i * 512);
        bf[0] = *(const bf16x8*)(lb);
        bf[1] = *(const bf16x8*)(lb + 512);
        if (t + 3 < NT) STAGE_A((t + 3) & 3, (t + 3) * 32);
        SBAR();
        __builtin_amdgcn_s_setprio(1);
#pragma unroll
        for (int i = 0; i < 8; ++i) {
            acc[i][0] = __builtin_amdgcn_mfma_f32_16x16x32_bf16(af[i], bf[0], acc[i][0], 0, 0, 0);
            acc[i][1] = __builtin_amdgcn_mfma_f32_16x16x32_bf16(af[i], bf[1], acc[i][1], 0, 0, 0);
        }
        __builtin_amdgcn_s_setprio(0);
        SBAR();

        // ---- phase 2: read B n2-3, stage next B unit, counted vmcnt, MFMA quadrant ----
        bf[2] = *(const bf16x8*)(lb + 1024);
        bf[3] = *(const bf16x8*)(lb + 1536);
        if (t + 3 < NT) STAGE_B((t + 3) & 3, (t + 3) * 32);
        __builtin_amdgcn_sched_barrier(0);
        // steady state: in-flight = tiles t+2,t+3 (8 loads) after wait -> tile t+1 ready
        if (t < NT - 3)       { asm volatile("s_waitcnt vmcnt(8)" ::: "memory"); }
        else if (t == NT - 3) { asm volatile("s_waitcnt vmcnt(4)" ::: "memory"); }
        else if (t == NT - 2) { asm volatile("s_waitcnt vmcnt(0)" ::: "memory"); }
        SBAR();
        __builtin_amdgcn_s_setprio(1);
#pragma unroll
        for (int i = 0; i < 8; ++i) {
            acc[i][2] = __builtin_amdgcn_mfma_f32_16x16x32_bf16(af[i], bf[2], acc[i][2], 0, 0, 0);
            acc[i][3] = __builtin_amdgcn_mfma_f32_16x16x32_bf16(af[i], bf[3], acc[i][3], 0, 0, 0);
        }
        __builtin_amdgcn_s_setprio(0);
        SBAR();
    }
#undef STAGE_A
#undef STAGE_B

    // C/D layout (m89-verified): col = lane&15, row = (lane>>4)*4 + j
    const int crow = brow + wr * 128 + fq * 4;
    const int ccol = bcol + wc * 64 + fr;
    if (OUT_F32) {
        float* C = (float*)Cv;
#pragma unroll
        for (int i = 0; i < 8; ++i)
#pragma unroll
            for (int nn = 0; nn < 4; ++nn)
#pragma unroll
                for (int j = 0; j < 4; ++j)
                    C[(size_t)(crow + i * 16 + j) * N + ccol + nn * 16] = acc[i][nn][j];
    } else {
        u16* C = (u16*)Cv;
#pragma unroll
        for (int i = 0; i < 8; ++i)
#pragma unroll
            for (int nn = 0; nn < 4; ++nn)
#pragma unroll
                for (int j = 0; j < 4; ++j)
                    C[(size_t)(crow + i * 16 + j) * N + ccol + nn * 16] = f2bf(acc[i][nn][j]);
    }
}

extern "C" void kernel_launch(void* const* d_in, const int* in_sizes, int n_in,
                              void* d_out, int out_size, void* d_ws, size_t ws_size,
                              hipStream_t stream) {
    const float* x  = (const float*)d_in[0];   // [4,2048,4096]
    const float* U  = (const float*)d_in[1];   // [4096,4096]
    const float* S  = (const float*)d_in[2];   // [4096]
    const float* Vh = (const float*)d_in[3];   // [4096,4096]
    float* out = (float*)d_out;                // [4,2048,4096] f32

    const int DIN = 4096, DOUT = 4096, R = 4096;
    const int Mx = 4 * 2048;

    u16* Xb = (u16*)d_ws;                                      // 64MB
    u16* Wb = (u16*)((char*)d_ws + (size_t)Mx * DIN * 2);      // 32MB
    u16* Ub   = (u16*)d_out;                                   // 32MB (dead before GEMM2)
    u16* SVhT = (u16*)((char*)d_out + (size_t)DOUT * R * 2);   // 32MB (dead before GEMM2)

    cvt_f32_bf16<<<2048, 256, 0, stream>>>((const float4*)x, (ushort4*)Xb, Mx * DIN / 4);
    cvt_f32_bf16<<<1024, 256, 0, stream>>>((const float4*)U, (ushort4*)Ub, DOUT * R / 4);
    svh_transpose<<<(R / 64) * (DIN / 64), 256, 0, stream>>>(Vh, S, SVhT, R, DIN);
    // GEMM1: Wb[o][i] = sum_r Ub[o][r] * SVhT[i][r]   (bf16 out)
    gemm_nt_pipe<0><<<(DOUT / 256) * (DIN / 256), 512, 0, stream>>>(Ub, SVhT, (void*)Wb, DOUT, DIN, R);
    // GEMM2: out[m][o] = sum_d Xb[m][d] * Wb[o][d]    (f32 out)
    gemm_nt_pipe<1><<<(Mx / 256) * (DOUT / 256), 512, 0, stream>>>(Xb, Wb, (void*)out, Mx, DOUT, DIN);
}